// Round 2
// baseline (387.623 us; speedup 1.0000x reference)
//
#include <hip/hip_runtime.h>

#define N_CH 1000000
#define N_POP (N_CH * 4)
#define N_INH (N_CH * 2)
#define SUBSTEPS 8

// Izhikevich update, exactly matching reference op order:
//   v += 0.04 v^2 + 5 v + 140 - u + I
//   u += a*(b*v_new - u)
//   spike = v_new >= 30
//   r = 0.9 r + 0.1 spike
//   v = spike ? c : v ; u = spike ? u + d : u
__device__ __forceinline__ void izh(float& v, float& u, float& r, float I,
                                    float a, float b, float cc, float d) {
    v = v + (0.04f * v * v + 5.0f * v + 140.0f - u + I);
    u = u + a * (b * v - u);
    bool spike = (v >= 30.0f);
    r = 0.9f * r + (spike ? 0.1f : 0.0f);
    if (spike) { v = cc; u = u + d; }
}

__global__ __launch_bounds__(256)
void pcc_kernel(const float* __restrict__ sens,
                const float* __restrict__ pred,
                const float* __restrict__ noise_pop,
                const float* __restrict__ noise_inh,
                const float* __restrict__ v_up, const float* __restrict__ u_up, const float* __restrict__ r_up,
                const float* __restrict__ v_dn, const float* __restrict__ u_dn, const float* __restrict__ r_dn,
                const float* __restrict__ v_dp, const float* __restrict__ u_dp, const float* __restrict__ r_dp,
                const float* __restrict__ v_in, const float* __restrict__ u_in, const float* __restrict__ r_in,
                const float* __restrict__ pred_bias,
                const float* __restrict__ elig_in,
                float* __restrict__ out,
                double* __restrict__ fe_acc) {
    const int c = blockIdx.x * blockDim.x + threadIdx.x;
    const bool active = (c < N_CH);

    float fe = 0.0f;

    if (active) {
        // ---- per-channel scalars ----
        const float sd = sens[c];
        const float pb = pred_bias[c];
        const float pred_total = pred[c] + pb;
        const float I_sens_base  = sd * 15.0f;              // G_SENS
        const float I_pred_base  = pred_total * 12.0f;      // G_PRED_INH
        const float I_sp_dn_base = I_pred_base - sd * 5.0f; // - G_PREC*sens

        // ---- state (float4 / float2 vector loads, channel-major) ----
        const float4* vup4 = (const float4*)v_up;
        const float4* uup4 = (const float4*)u_up;
        const float4* rup4 = (const float4*)r_up;
        const float4* vdn4 = (const float4*)v_dn;
        const float4* udn4 = (const float4*)u_dn;
        const float4* rdn4 = (const float4*)r_dn;
        const float4* vdp4 = (const float4*)v_dp;
        const float4* udp4 = (const float4*)u_dp;
        const float4* rdp4 = (const float4*)r_dp;
        const float2* vin2 = (const float2*)v_in;
        const float2* uin2 = (const float2*)u_in;
        const float2* rin2 = (const float2*)r_in;

        float4 vu = vup4[c], uu = uup4[c], ru = rup4[c];
        float4 vd = vdn4[c], ud = udn4[c], rd = rdn4[c];
        float4 vp = vdp4[c], up = udp4[c], rp = rdp4[c];
        float2 vi = vin2[c], ui = uin2[c], ri = rin2[c];

        const float4* np4base = (const float4*)noise_pop;
        const float2* ni2base = (const float2*)noise_inh;

        #pragma unroll
        for (int s = 0; s < SUBSTEPS; ++s) {
            float4 np = np4base[(size_t)s * (N_POP / 4) + c];
            float2 ni = ni2base[(size_t)s * (N_INH / 2) + c];
            np.x *= 0.4f; np.y *= 0.4f; np.z *= 0.4f; np.w *= 0.4f;
            ni.x *= 0.4f; ni.y *= 0.4f;

            // ascending error uses PREVIOUS substep rates
            const float ru_pool = 0.25f * (ru.x + ru.y + ru.z + ru.w);
            const float rd_pool = 0.25f * (rd.x + rd.y + rd.z + rd.w);
            const float I_asc = ru_pool * 8.0f - rd_pool * 4.0f;

            // deep pyramidal (IB: a=0.02 b=0.2 c=-55 d=4, tonic 0)
            const float Idp = I_pred_base + I_asc;
            izh(vp.x, up.x, rp.x, Idp + np.x, 0.02f, 0.2f, -55.0f, 4.0f);
            izh(vp.y, up.y, rp.y, Idp + np.y, 0.02f, 0.2f, -55.0f, 4.0f);
            izh(vp.z, up.z, rp.z, Idp + np.z, 0.02f, 0.2f, -55.0f, 4.0f);
            izh(vp.w, up.w, rp.w, Idp + np.w, 0.02f, 0.2f, -55.0f, 4.0f);

            // inhibitory (FS: a=0.1 b=0.2 c=-65 d=2, tonic -0.5)
            const float rp_pool = 0.25f * (rp.x + rp.y + rp.z + rp.w);
            const float I_in_base = rp_pool * 12.0f;
            izh(vi.x, ui.x, ri.x, I_in_base + ni.x - 0.5f, 0.10f, 0.2f, -65.0f, 2.0f);
            izh(vi.y, ui.y, ri.y, I_in_base + ni.y - 0.5f, 0.10f, 0.2f, -65.0f, 2.0f);

            // under-prediction error (RS: a=0.02 b=0.2 c=-65 d=8, tonic -1)
            const float inh_ch = 0.5f * (ri.x + ri.y);
            const float Iup = I_sens_base - inh_ch * 5.0f - 1.0f;
            izh(vu.x, uu.x, ru.x, Iup + np.x, 0.02f, 0.2f, -65.0f, 8.0f);
            izh(vu.y, uu.y, ru.y, Iup + np.y, 0.02f, 0.2f, -65.0f, 8.0f);
            izh(vu.z, uu.z, ru.z, Iup + np.z, 0.02f, 0.2f, -65.0f, 8.0f);
            izh(vu.w, uu.w, ru.w, Iup + np.w, 0.02f, 0.2f, -65.0f, 8.0f);

            // over-prediction error (RS, tonic -1)
            const float Idn = I_sp_dn_base - 1.0f;
            izh(vd.x, ud.x, rd.x, Idn + np.x, 0.02f, 0.2f, -65.0f, 8.0f);
            izh(vd.y, ud.y, rd.y, Idn + np.y, 0.02f, 0.2f, -65.0f, 8.0f);
            izh(vd.z, ud.z, rd.z, Idn + np.z, 0.02f, 0.2f, -65.0f, 8.0f);
            izh(vd.w, ud.w, rd.w, Idn + np.w, 0.02f, 0.2f, -65.0f, 8.0f);
        }

        // ---- outputs ----
        const float sp_up_ch = 0.25f * (ru.x + ru.y + ru.z + ru.w);
        const float sp_dn_ch = 0.25f * (rd.x + rd.y + rd.z + rd.w);
        const float dp_ch    = 0.25f * (rp.x + rp.y + rp.z + rp.w);
        const float pe_signed = sp_up_ch - sp_dn_ch;
        const float pe_mag    = sp_up_ch + sp_dn_ch;
        fe = 2.5f * pe_mag * pe_mag;  // 0.5 * G_PREC * pe_mag^2

        const float elig_new = elig_in[c] * 0.9f + (sp_up_ch * sd - sp_dn_ch * dp_ch);
        float pbn = pb + 0.005f * elig_new;
        pbn = fminf(fmaxf(pbn, -2.0f), 2.0f);
        const float precision_grad = 0.5f / (5.0f + 1e-4f) - 0.5f * pe_signed * pe_signed;
        float gpn = 5.0f + 0.001f * precision_grad;
        gpn = fminf(fmaxf(gpn, 0.5f), 15.0f);

        out[c] = pe_signed;                       // pe_signed
        out[N_CH + c] = pe_mag;                   // pe_magnitude
        // out[2*N_CH] is free_energy (scalar), written by fe_write_kernel
        out[2 * N_CH + 1 + c] = gpn;              // g_prec_new
        out[3 * N_CH + 1 + c] = dp_ch;            // dp_ch
        out[4 * N_CH + 1 + c] = sp_up_ch;         // sp_up_ch
        out[5 * N_CH + 1 + c] = sp_dn_ch;         // sp_dn_ch
        out[6 * N_CH + 1 + c] = pbn;              // pred_bias_new
        out[7 * N_CH + 1 + c] = elig_new;         // elig
    }

    // ---- free-energy block reduction (all threads participate) ----
    #pragma unroll
    for (int off = 32; off > 0; off >>= 1)
        fe += __shfl_down(fe, off, 64);
    __shared__ float sred[4];
    const int lane = threadIdx.x & 63;
    const int wid  = threadIdx.x >> 6;
    if (lane == 0) sred[wid] = fe;
    __syncthreads();
    if (threadIdx.x == 0) {
        const double tot = (double)sred[0] + (double)sred[1]
                         + (double)sred[2] + (double)sred[3];
        atomicAdd(fe_acc, tot);
    }
}

__global__ void fe_write_kernel(const double* __restrict__ fe_acc,
                                float* __restrict__ out) {
    out[2 * N_CH] = (float)(*fe_acc);
}

extern "C" void kernel_launch(void* const* d_in, const int* in_sizes, int n_in,
                              void* d_out, int out_size, void* d_ws, size_t ws_size,
                              hipStream_t stream) {
    const float* sens      = (const float*)d_in[0];
    const float* pred      = (const float*)d_in[1];
    const float* noise_pop = (const float*)d_in[2];
    const float* noise_inh = (const float*)d_in[3];
    const float* v_up = (const float*)d_in[4];
    const float* u_up = (const float*)d_in[5];
    const float* r_up = (const float*)d_in[6];
    const float* v_dn = (const float*)d_in[7];
    const float* u_dn = (const float*)d_in[8];
    const float* r_dn = (const float*)d_in[9];
    const float* v_dp = (const float*)d_in[10];
    const float* u_dp = (const float*)d_in[11];
    const float* r_dp = (const float*)d_in[12];
    const float* v_in = (const float*)d_in[13];
    const float* u_in = (const float*)d_in[14];
    const float* r_in = (const float*)d_in[15];
    const float* pred_bias = (const float*)d_in[16];
    const float* elig      = (const float*)d_in[17];
    float* out = (float*)d_out;
    double* fe_acc = (double*)d_ws;   // 8-byte accumulator in scratch

    // d_ws is poisoned 0xAA before every timed launch — zero the accumulator
    // (async memset is graph-capture safe).
    hipMemsetAsync(fe_acc, 0, sizeof(double), stream);

    const int threads = 256;
    const int blocks = (N_CH + threads - 1) / threads;
    pcc_kernel<<<blocks, threads, 0, stream>>>(
        sens, pred, noise_pop, noise_inh,
        v_up, u_up, r_up, v_dn, u_dn, r_dn,
        v_dp, u_dp, r_dp, v_in, u_in, r_in,
        pred_bias, elig, out, fe_acc);
    fe_write_kernel<<<1, 1, 0, stream>>>(fe_acc, out);
}

// Round 4
// 386.942 us; speedup vs baseline: 1.0018x; 1.0018x over previous
//
#include <hip/hip_runtime.h>

#define N_CH 1000000
#define N_POP (N_CH * 4)
#define N_INH (N_CH * 2)
#define SUBSTEPS 8

// Izhikevich update, exactly matching reference op order:
//   v += 0.04 v^2 + 5 v + 140 - u + I
//   u += a*(b*v_new - u)
//   spike = v_new >= 30
//   r = 0.9 r + 0.1 spike
//   v = spike ? c : v ; u = spike ? u + d : u
__device__ __forceinline__ void izh(float& v, float& u, float& r, float I,
                                    float a, float b, float cc, float d) {
    v = v + (0.04f * v * v + 5.0f * v + 140.0f - u + I);
    u = u + a * (b * v - u);
    bool spike = (v >= 30.0f);
    r = 0.9f * r + (spike ? 0.1f : 0.0f);
    if (spike) { v = cc; u = u + d; }
}

// __launch_bounds__(256, 4): 4 waves/SIMD minimum -> compiler may use up to
// ~128 VGPRs. We WANT ~110 so the 48 floats of noise can be prefetched into
// registers before the dependency chain starts (round-2 profile: VGPR=44,
// loads sunk into the loop, VALUBusy 26% = exposed memory latency).
__global__ __launch_bounds__(256, 4)
void pcc_kernel(const float* __restrict__ sens,
                const float* __restrict__ pred,
                const float* __restrict__ noise_pop,
                const float* __restrict__ noise_inh,
                const float* __restrict__ v_up, const float* __restrict__ u_up, const float* __restrict__ r_up,
                const float* __restrict__ v_dn, const float* __restrict__ u_dn, const float* __restrict__ r_dn,
                const float* __restrict__ v_dp, const float* __restrict__ u_dp, const float* __restrict__ r_dp,
                const float* __restrict__ v_in, const float* __restrict__ u_in, const float* __restrict__ r_in,
                const float* __restrict__ pred_bias,
                const float* __restrict__ elig_in,
                float* __restrict__ out,
                double* __restrict__ fe_acc) {
    const int c = blockIdx.x * blockDim.x + threadIdx.x;
    const bool active = (c < N_CH);

    float fe = 0.0f;

    if (active) {
        // ---- prefetch ALL memory first: noise (48 floats) + state + scalars.
        // These loads have no dependence on the compute chain; issuing them
        // back-to-back overlaps their latency with each other instead of
        // serializing one load per substep.
        const float4* np4base = (const float4*)noise_pop;
        const float2* ni2base = (const float2*)noise_inh;
        float4 np_s[SUBSTEPS];
        float2 ni_s[SUBSTEPS];
        #pragma unroll
        for (int s = 0; s < SUBSTEPS; ++s) {
            np_s[s] = np4base[(size_t)s * (N_POP / 4) + c];
            ni_s[s] = ni2base[(size_t)s * (N_INH / 2) + c];
        }

        const float sd = sens[c];
        const float pb = pred_bias[c];
        const float pred_total = pred[c] + pb;
        const float el0 = elig_in[c];

        const float4* vup4 = (const float4*)v_up;
        const float4* uup4 = (const float4*)u_up;
        const float4* rup4 = (const float4*)r_up;
        const float4* vdn4 = (const float4*)v_dn;
        const float4* udn4 = (const float4*)u_dn;
        const float4* rdn4 = (const float4*)r_dn;
        const float4* vdp4 = (const float4*)v_dp;
        const float4* udp4 = (const float4*)u_dp;
        const float4* rdp4 = (const float4*)r_dp;
        const float2* vin2 = (const float2*)v_in;
        const float2* uin2 = (const float2*)u_in;
        const float2* rin2 = (const float2*)r_in;

        float4 vu = vup4[c], uu = uup4[c], ru = rup4[c];
        float4 vd = vdn4[c], ud = udn4[c], rd = rdn4[c];
        float4 vp = vdp4[c], up = udp4[c], rp = rdp4[c];
        float2 vi = vin2[c], ui = uin2[c], ri = rin2[c];

        // keep the compiler from sinking the prefetch back into the loop
        asm volatile("" ::: "memory");

        const float I_sens_base  = sd * 15.0f;              // G_SENS
        const float I_pred_base  = pred_total * 12.0f;      // G_PRED_INH
        const float I_sp_dn_base = I_pred_base - sd * 5.0f; // - G_PREC*sens

        #pragma unroll
        for (int s = 0; s < SUBSTEPS; ++s) {
            float4 np = np_s[s];
            float2 ni = ni_s[s];
            np.x *= 0.4f; np.y *= 0.4f; np.z *= 0.4f; np.w *= 0.4f;
            ni.x *= 0.4f; ni.y *= 0.4f;

            // ascending error uses PREVIOUS substep rates
            const float ru_pool = 0.25f * (ru.x + ru.y + ru.z + ru.w);
            const float rd_pool = 0.25f * (rd.x + rd.y + rd.z + rd.w);
            const float I_asc = ru_pool * 8.0f - rd_pool * 4.0f;

            // deep pyramidal (IB: a=0.02 b=0.2 c=-55 d=4, tonic 0)
            const float Idp = I_pred_base + I_asc;
            izh(vp.x, up.x, rp.x, Idp + np.x, 0.02f, 0.2f, -55.0f, 4.0f);
            izh(vp.y, up.y, rp.y, Idp + np.y, 0.02f, 0.2f, -55.0f, 4.0f);
            izh(vp.z, up.z, rp.z, Idp + np.z, 0.02f, 0.2f, -55.0f, 4.0f);
            izh(vp.w, up.w, rp.w, Idp + np.w, 0.02f, 0.2f, -55.0f, 4.0f);

            // inhibitory (FS: a=0.1 b=0.2 c=-65 d=2, tonic -0.5)
            const float rp_pool = 0.25f * (rp.x + rp.y + rp.z + rp.w);
            const float I_in_base = rp_pool * 12.0f;
            izh(vi.x, ui.x, ri.x, I_in_base + ni.x - 0.5f, 0.10f, 0.2f, -65.0f, 2.0f);
            izh(vi.y, ui.y, ri.y, I_in_base + ni.y - 0.5f, 0.10f, 0.2f, -65.0f, 2.0f);

            // under-prediction error (RS: a=0.02 b=0.2 c=-65 d=8, tonic -1)
            const float inh_ch = 0.5f * (ri.x + ri.y);
            const float Iup = I_sens_base - inh_ch * 5.0f - 1.0f;
            izh(vu.x, uu.x, ru.x, Iup + np.x, 0.02f, 0.2f, -65.0f, 8.0f);
            izh(vu.y, uu.y, ru.y, Iup + np.y, 0.02f, 0.2f, -65.0f, 8.0f);
            izh(vu.z, uu.z, ru.z, Iup + np.z, 0.02f, 0.2f, -65.0f, 8.0f);
            izh(vu.w, uu.w, ru.w, Iup + np.w, 0.02f, 0.2f, -65.0f, 8.0f);

            // over-prediction error (RS, tonic -1)
            const float Idn = I_sp_dn_base - 1.0f;
            izh(vd.x, ud.x, rd.x, Idn + np.x, 0.02f, 0.2f, -65.0f, 8.0f);
            izh(vd.y, ud.y, rd.y, Idn + np.y, 0.02f, 0.2f, -65.0f, 8.0f);
            izh(vd.z, ud.z, rd.z, Idn + np.z, 0.02f, 0.2f, -65.0f, 8.0f);
            izh(vd.w, ud.w, rd.w, Idn + np.w, 0.02f, 0.2f, -65.0f, 8.0f);
        }

        // ---- outputs ----
        const float sp_up_ch = 0.25f * (ru.x + ru.y + ru.z + ru.w);
        const float sp_dn_ch = 0.25f * (rd.x + rd.y + rd.z + rd.w);
        const float dp_ch    = 0.25f * (rp.x + rp.y + rp.z + rp.w);
        const float pe_signed = sp_up_ch - sp_dn_ch;
        const float pe_mag    = sp_up_ch + sp_dn_ch;
        fe = 2.5f * pe_mag * pe_mag;  // 0.5 * G_PREC * pe_mag^2

        const float elig_new = el0 * 0.9f + (sp_up_ch * sd - sp_dn_ch * dp_ch);
        float pbn = pb + 0.005f * elig_new;
        pbn = fminf(fmaxf(pbn, -2.0f), 2.0f);
        const float precision_grad = 0.5f / (5.0f + 1e-4f) - 0.5f * pe_signed * pe_signed;
        float gpn = 5.0f + 0.001f * precision_grad;
        gpn = fminf(fmaxf(gpn, 0.5f), 15.0f);

        float* __restrict__ o2 = out + (2 * N_CH + 1);
        out[c] = pe_signed;                       // pe_signed
        out[N_CH + c] = pe_mag;                   // pe_magnitude
        // out[2*N_CH] is free_energy (scalar), written by fe_write_kernel
        o2[c] = gpn;                              // g_prec_new
        o2[N_CH + c] = dp_ch;                     // dp_ch
        o2[2 * N_CH + c] = sp_up_ch;              // sp_up_ch
        o2[3 * N_CH + c] = sp_dn_ch;              // sp_dn_ch
        o2[4 * N_CH + c] = pbn;                   // pred_bias_new
        o2[5 * N_CH + c] = elig_new;              // elig
    }

    // ---- free-energy block reduction (all threads participate) ----
    #pragma unroll
    for (int off = 32; off > 0; off >>= 1)
        fe += __shfl_down(fe, off, 64);
    __shared__ float sred[4];
    const int lane = threadIdx.x & 63;
    const int wid  = threadIdx.x >> 6;
    if (lane == 0) sred[wid] = fe;
    __syncthreads();
    if (threadIdx.x == 0) {
        const double tot = (double)sred[0] + (double)sred[1]
                         + (double)sred[2] + (double)sred[3];
        atomicAdd(fe_acc, tot);
    }
}

__global__ void fe_write_kernel(const double* __restrict__ fe_acc,
                                float* __restrict__ out) {
    out[2 * N_CH] = (float)(*fe_acc);
}

extern "C" void kernel_launch(void* const* d_in, const int* in_sizes, int n_in,
                              void* d_out, int out_size, void* d_ws, size_t ws_size,
                              hipStream_t stream) {
    const float* sens      = (const float*)d_in[0];
    const float* pred      = (const float*)d_in[1];
    const float* noise_pop = (const float*)d_in[2];
    const float* noise_inh = (const float*)d_in[3];
    const float* v_up = (const float*)d_in[4];
    const float* u_up = (const float*)d_in[5];
    const float* r_up = (const float*)d_in[6];
    const float* v_dn = (const float*)d_in[7];
    const float* u_dn = (const float*)d_in[8];
    const float* r_dn = (const float*)d_in[9];
    const float* v_dp = (const float*)d_in[10];
    const float* u_dp = (const float*)d_in[11];
    const float* r_dp = (const float*)d_in[12];
    const float* v_in = (const float*)d_in[13];
    const float* u_in = (const float*)d_in[14];
    const float* r_in = (const float*)d_in[15];
    const float* pred_bias = (const float*)d_in[16];
    const float* elig      = (const float*)d_in[17];
    float* out = (float*)d_out;
    double* fe_acc = (double*)d_ws;   // 8-byte accumulator in scratch

    // d_ws is poisoned 0xAA before every timed launch — zero the accumulator
    // (async memset is graph-capture safe).
    hipMemsetAsync(fe_acc, 0, sizeof(double), stream);

    const int threads = 256;
    const int blocks = (N_CH + threads - 1) / threads;
    pcc_kernel<<<blocks, threads, 0, stream>>>(
        sens, pred, noise_pop, noise_inh,
        v_up, u_up, r_up, v_dn, u_dn, r_dn,
        v_dp, u_dp, r_dp, v_in, u_in, r_in,
        pred_bias, elig, out, fe_acc);
    fe_write_kernel<<<1, 1, 0, stream>>>(fe_acc, out);
}